// Round 8
// baseline (3699.681 us; speedup 1.0000x reference)
//
#include <hip/hip_runtime.h>

#define Bdim 64
#define Tdim 512
#define Fdim 512
#define Hdim 1024
#define NKB  48          // K-blocks of 32: 16 for x (K=512) + 32 for h (K=1024)
#define NXKB 16
#define NHKB 32
#define NWG  128
#define NTHR 256

typedef __attribute__((ext_vector_type(8))) _Float16            f16x8;
typedef __attribute__((ext_vector_type(4))) float               f32x4;

#define MFMA(a, b, c) __builtin_amdgcn_mfma_f32_16x16x32_f16((a), (b), (c), 0, 0, 0)

// ---- workspace layout (bytes) ----
// Wp    : fp16 fragment-linear weights, 12.6 MB
// bias_p: fp32[4096]
// hbuf  : fp16[2][128 wg][64 b][8 c]  (2 x 128 KiB, compact per-WG blocks)
// flags : uint[NWG] padded to one 128B line each (stride 32 uints)
// dummy : 2 KiB sink for the t=0 placeholder out-store
#define WP_ELEMS  (256*48*64*8)
#define BIAS_OFF  ((size_t)WP_ELEMS * 2)
#define HBUF_OFF  (BIAS_OFF + 4096 * 4)
#define HBUF_HALF 65536                              // halves per buffer (64*1024)
#define FLAG_OFF  (HBUF_OFF + (size_t)2 * HBUF_HALF * 2)
#define FLAG_STRIDE 32                               // uints (128 B) per flag
#define DUMMY_OFF (FLAG_OFF + (size_t)NWG * FLAG_STRIDE * 4)

__device__ __forceinline__ float sigmoidf_(float v) {
    return 1.0f / (1.0f + __expf(-v));
}
__device__ __forceinline__ float tanhf_(float v) {
    return 1.0f - 2.0f / (1.0f + __expf(2.0f * v));
}

// Device-coherent (L1+L2 bypass) 16B load: data written via agent-scope
// write-through stores lives at the MALL; sc0 sc1 reads it fresh.
__device__ __forceinline__ f16x8 uload16(const void* p) {
    f16x8 r;
    asm volatile("global_load_dwordx4 %0, %1, off sc0 sc1"
                 : "=v"(r) : "v"(p) : "memory");
    return r;
}
// Compiler-invisible (for waitcnt bookkeeping) plain 8B store.
__device__ __forceinline__ void ustore8(void* p, float2 v) {
    asm volatile("global_store_dwordx2 %0, %1, off" :: "v"(p), "v"(v) : "memory");
}

// Counted vmcnt wait (in-order retirement) + scheduling fence (rule #18)
#define WAITV(N) do { asm volatile("s_waitcnt vmcnt(" #N ")" ::: "memory"); \
                      __builtin_amdgcn_sched_barrier(0); } while (0)

// Packed col Np = wg*32 + gate*8 + c  <->  orig col n = gate*1024 + wg*8 + c.
// Wp8[(tile*48 + kb)*64 + lane] = Wfull[kb*32 + (lane>>4)*8 + j][orig(tile*16 + (lane&15))]
__global__ void pack_w_kernel(const float* __restrict__ Wi, const float* __restrict__ Wh,
                              _Float16* __restrict__ Wp)
{
    int d = blockIdx.x * blockDim.x + threadIdx.x;   // 0 .. 786431
    int tn   = d / 3072;
    int r    = d % 3072;
    int kb   = r / 64;
    int lane = r % 64;
    int kg = lane >> 4, lm = lane & 15;
    int Np = tn * 16 + lm;
    int g    = Np >> 5;
    int lc   = Np & 31;
    int gate = lc >> 3, c = lc & 7;
    int n  = gate * Hdim + g * 8 + c;
    int k0 = kb * 32 + kg * 8;
    f16x8 v;
#pragma unroll
    for (int j = 0; j < 8; ++j) {
        int k = k0 + j;
        float w = (k < Fdim) ? Wi[(long)k * 4096 + n] : Wh[(long)(k - Fdim) * 4096 + n];
        v[j] = (_Float16)w;
    }
    ((f16x8*)Wp)[d] = v;
}

__global__ void pack_misc_kernel(const float* __restrict__ bh, const float* __restrict__ h0,
                                 float* __restrict__ bias_p, _Float16* __restrict__ hbuf,
                                 unsigned int* __restrict__ flags)
{
    int t = blockIdx.x * blockDim.x + threadIdx.x;   // 0 .. 65535
    if (t < NWG) flags[t * FLAG_STRIDE] = 0u;        // re-armed every launch
    if (t < 4096) {
        int g = t >> 5, lc = t & 31;
        int gate = lc >> 3, c = lc & 7;
        bias_p[t] = bh[gate * Hdim + g * 8 + c];
    }
    {   // hbuf buffer 0 = h at t=0, compact layout [wg'][b][c]
        int wgp = t >> 9;
        int b   = (t >> 3) & 63;
        int c   = t & 7;
        hbuf[t] = (_Float16)h0[b * Hdim + wgp * 8 + c];
    }
}

__global__ __launch_bounds__(NTHR, 1)
void lstm_kernel(const float* __restrict__ x, const float* __restrict__ c0,
                 const f16x8* __restrict__ Wp8, const float* __restrict__ bias_p,
                 _Float16* __restrict__ hbuf, unsigned int* __restrict__ flags,
                 float* __restrict__ dummy, float* __restrict__ out)
{
    __shared__ f16x8 wlds[2 * NKB * 64];              // 96 KiB weight slice
    __shared__ float zlds[Bdim][33];                  // 8.25 KiB (per-wave 16-row slices)

    // XCD-grouped logical wg (keeps out-line sharers on one XCD)
    const int wg   = (blockIdx.x & 7) * 16 + (blockIdx.x >> 3);
    const int tid  = threadIdx.x;
    const int wave = tid >> 6;
    const int lane = tid & 63;
    const int kg = lane >> 4;
    const int lm = lane & 15;

    // ---- stage the WG's weight slice into LDS once ----
    {
        const f16x8* src = Wp8 + (size_t)wg * 2 * NKB * 64;
        for (int e = tid; e < 2 * NKB * 64; e += NTHR) wlds[e] = src[e];
    }

    const float bias0 = bias_p[wg * 32 + lm];
    const float bias1 = bias_p[wg * 32 + 16 + lm];

    // gate-phase ownership (per-wave): wave w, lane l owns batch row
    // grow = 16w + (l>>2), cols gjl, gjl+1 where gjl = (l&3)*2.
    const int grow = wave * 16 + (lane >> 2);
    const int gjl  = (lane & 3) * 2;
    float cc0 = c0[grow * Hdim + wg * 8 + gjl];
    float cc1 = c0[grow * Hdim + wg * 8 + gjl + 1];

    const int arow = wave * 16 + lm;                  // MFMA A-operand row (batch)
    const float* __restrict__ xrow = x + (size_t)arow * Tdim * Fdim + kg * 8;

    // per-lane h' read base (bytes): frag kb at +kb*4096
    const char* __restrict__ hrdbase =
        (const char*)hbuf + (size_t)kg * 1024 + (size_t)arow * 16;

    // pending out-store (previous step's h values); t=0 -> dummy sink
    float2 pv = {0.f, 0.f};
    float* pa = dummy + tid * 2;

    __syncthreads();                                  // wlds ready

    for (int t = 0; t < Tdim; ++t) {
        const int cur = t & 1;
        const unsigned int gen = (unsigned int)t;

        // ---- flag prefetch (wave 0): issue now, check after x-phase ----
        unsigned int pf0 = 0, pf1 = 0;
        if (t && wave == 0) {
            pf0 = __hip_atomic_load(flags + (size_t)lane * FLAG_STRIDE,
                                    __ATOMIC_RELAXED, __HIP_MEMORY_SCOPE_AGENT);
            pf1 = __hip_atomic_load(flags + (size_t)(64 + lane) * FLAG_STRIDE,
                                    __ATOMIC_RELAXED, __HIP_MEMORY_SCOPE_AGENT);
        }
        __builtin_amdgcn_sched_barrier(0);            // pin prefetch before x-phase

        f32x4 acc0a = {bias0, bias0, bias0, bias0};
        f32x4 acc1a = {bias1, bias1, bias1, bias1};
        f32x4 acc0b = {0.f, 0.f, 0.f, 0.f};
        f32x4 acc1b = {0.f, 0.f, 0.f, 0.f};

        // ---- x part of K: load + cvt + MFMA (transient regs);
        //      overlaps other WGs' h(t) publish latency + flag prefetch ----
        {
            const float* xt = xrow + (size_t)t * Fdim;
#pragma unroll 8
            for (int kb = 0; kb < NXKB; ++kb) {
                const f32x4* ap = (const f32x4*)(xt + kb * 32);
                f32x4 lo = ap[0];
                f32x4 hi = ap[1];
                f16x8 a;
#pragma unroll
                for (int j = 0; j < 4; ++j) { a[j] = (_Float16)lo[j]; a[4 + j] = (_Float16)hi[j]; }
                f16x8 bf0 = wlds[kb * 64 + lane];
                f16x8 bf1 = wlds[NKB * 64 + kb * 64 + lane];
                if (kb & 1) { acc0b = MFMA(a, bf0, acc0b); acc1b = MFMA(a, bf1, acc1b); }
                else        { acc0a = MFMA(a, bf0, acc0a); acc1a = MFMA(a, bf1, acc1a); }
            }
        }

        // ---- wave 0: fast check on prefetched flags; poll only on miss ----
        if (t && wave == 0) {
            if (!__all(pf0 >= gen && pf1 >= gen)) {
                while (true) {
                    unsigned int f0 = __hip_atomic_load(flags + (size_t)lane * FLAG_STRIDE,
                                                        __ATOMIC_RELAXED, __HIP_MEMORY_SCOPE_AGENT);
                    unsigned int f1 = __hip_atomic_load(flags + (size_t)(64 + lane) * FLAG_STRIDE,
                                                        __ATOMIC_RELAXED, __HIP_MEMORY_SCOPE_AGENT);
                    if (__all(f0 >= gen && f1 >= gen)) break;
                    __builtin_amdgcn_s_sleep(1);
                }
            }
        }
        __syncthreads();                              // (A) h(t) globally published

        // ---- h part of K: 2-group pipeline, counted vmcnt; out-store slotted in.
        //      In-order retirement; entering outstanding == 0. ----
        {
            const char* hq = hrdbase + (size_t)cur * (HBUF_HALF * 2);
            f16x8 hA[8], hB[8];

#define HLOAD(BASE, H)                                                  \
            _Pragma("unroll")                                           \
            for (int k = 0; k < 8; ++k)                                 \
                H[k] = uload16(hq + (size_t)((BASE) + k) * 4096);

#define HGROUP(BASE, H)                                                 \
            _Pragma("unroll")                                           \
            for (int k = 0; k < 8; ++k) {                               \
                int kb = (BASE) + k;                                    \
                f16x8 bf0 = wlds[(NXKB + kb) * 64 + lane];              \
                f16x8 bf1 = wlds[NKB * 64 + (NXKB + kb) * 64 + lane];   \
                if (kb & 1) { acc0b = MFMA(H[k], bf0, acc0b); acc1b = MFMA(H[k], bf1, acc1b); } \
                else        { acc0a = MFMA(H[k], bf0, acc0a); acc1a = MFMA(H[k], bf1, acc1a); } \
            }

            HLOAD(0,  hA);                            // L0..7   (8 outstanding)
            HLOAD(8,  hB);                            // L8..15  (16)
            WAITV(8);                                 // L0..7 done
            HGROUP(0,  hA);
            HLOAD(16, hA);                            // L16..23 (16)
            WAITV(8);                                 // L8..15 done
            HGROUP(8,  hB);
            HLOAD(24, hB);                            // L24..31 (16)
            ustore8(pa, pv);                          // prev-step out (17, youngest)
            WAITV(9);                                 // L16..23 done (out + 8 loads left)
            HGROUP(16, hA);
            WAITV(1);                                 // all loads done; out may linger
            HGROUP(24, hB);
#undef HLOAD
#undef HGROUP
        }
        f32x4 z0 = acc0a + acc0b;
        f32x4 z1 = acc1a + acc1b;

        // D layout: row = (lane>>4)*4 + r, col = lane&15  (wave-private rows)
        {
            int rbase = wave * 16 + kg * 4;
#pragma unroll
            for (int r = 0; r < 4; ++r) {
                zlds[rbase + r][lm]      = z0[r];
                zlds[rbase + r][16 + lm] = z1[r];
            }
        }
        // wave-local transpose readback: rows are per-wave, no __syncthreads
        asm volatile("s_waitcnt lgkmcnt(0)" ::: "memory");
        __builtin_amdgcn_sched_barrier(0);

        // ---- gates: all 256 lanes, 2 cols each (i=c, f=8+c, g=16+c, o=24+c) ----
        float hv0, hv1;
        {
            float i0 = sigmoidf_(zlds[grow][gjl]);
            float f0 = sigmoidf_(zlds[grow][8 + gjl]);
            float g0 = tanhf_(zlds[grow][16 + gjl]);
            float o0 = sigmoidf_(zlds[grow][24 + gjl]);
            cc0 = f0 * cc0 + i0 * g0;
            hv0 = o0 * tanhf_(cc0);

            float i1 = sigmoidf_(zlds[grow][gjl + 1]);
            float f1 = sigmoidf_(zlds[grow][8 + gjl + 1]);
            float g1 = tanhf_(zlds[grow][16 + gjl + 1]);
            float o1 = sigmoidf_(zlds[grow][24 + gjl + 1]);
            cc1 = f1 * cc1 + i1 * g1;
            hv1 = o1 * tanhf_(cc1);
        }

        // ---- publish h(t+1): pair-combine 4B->8B via shfl, even lanes store ----
        {
            union { _Float16 h[2]; unsigned int u; } pk;
            pk.h[0] = (_Float16)hv0; pk.h[1] = (_Float16)hv1;
            unsigned int nbu = __shfl(pk.u, lane ^ 1);
            if (!(lane & 1)) {
                unsigned long long v = (unsigned long long)pk.u
                                     | ((unsigned long long)nbu << 32);
                __hip_atomic_store((unsigned long long*)
                    (hbuf + (size_t)(cur ^ 1) * HBUF_HALF + (size_t)wg * 512
                          + (size_t)grow * 8 + gjl),
                    v, __ATOMIC_RELAXED, __HIP_MEMORY_SCOPE_AGENT);
            }
        }
        asm volatile("s_waitcnt vmcnt(0)" ::: "memory");   // h' (and out) acked
        __syncthreads();                              // (C) all waves drained
        if (tid == 0)
            __hip_atomic_store(flags + (size_t)wg * FLAG_STRIDE, (unsigned int)(t + 1),
                               __ATOMIC_RELAXED, __HIP_MEMORY_SCOPE_AGENT);

        // carry this step's out values; stored inside next step's h-phase
        pv.x = hv0; pv.y = hv1;
        pa = out + ((size_t)grow * Tdim + t) * Hdim + wg * 8 + gjl;
    }

    // epilogue: last step's out values
    *(float2*)pa = pv;
}

extern "C" void kernel_launch(void* const* d_in, const int* in_sizes, int n_in,
                              void* d_out, int out_size, void* d_ws, size_t ws_size,
                              hipStream_t stream)
{
    const float* x  = (const float*)d_in[0];
    const float* c0 = (const float*)d_in[1];
    const float* h0 = (const float*)d_in[2];
    const float* Wi = (const float*)d_in[3];
    const float* Wh = (const float*)d_in[4];
    const float* bh = (const float*)d_in[5];
    float* out = (float*)d_out;

    char* ws = (char*)d_ws;
    _Float16*     Wp     = (_Float16*)(ws);
    float*        bias_p = (float*)(ws + BIAS_OFF);
    _Float16*     hbuf   = (_Float16*)(ws + HBUF_OFF);
    unsigned int* flags  = (unsigned int*)(ws + FLAG_OFF);
    float*        dummy  = (float*)(ws + DUMMY_OFF);

    hipLaunchKernelGGL(pack_w_kernel,    dim3(3072), dim3(256), 0, stream, Wi, Wh, Wp);
    hipLaunchKernelGGL(pack_misc_kernel, dim3(256),  dim3(256), 0, stream, bh, h0, bias_p, hbuf, flags);
    hipLaunchKernelGGL(lstm_kernel, dim3(NWG), dim3(NTHR), 0, stream,
                       x, c0, (const f16x8*)Wp, bias_p, hbuf, flags, dummy, out);
}

// Round 9
// 3637.061 us; speedup vs baseline: 1.0172x; 1.0172x over previous
//
#include <hip/hip_runtime.h>

#define Bdim 64
#define Tdim 512
#define Fdim 512
#define Hdim 1024
#define NKB  48          // K-blocks of 32: 16 for x (K=512) + 32 for h (K=1024)
#define NXKB 16
#define NHKB 32
#define NWG  128
#define NTHR 256
#define NSLOT 4

typedef __attribute__((ext_vector_type(8))) _Float16     f16x8;
typedef __attribute__((ext_vector_type(4))) float        f32x4;
typedef __attribute__((ext_vector_type(4))) unsigned int u32x4;

#define MFMA(a, b, c) __builtin_amdgcn_mfma_f32_16x16x32_f16((a), (b), (c), 0, 0, 0)

// ---- workspace layout (bytes) ----
// Wp    : fp16 fragment-linear weights, 12.6 MB
// bias_p: fp32[4096]
// hbuf  : fp16[4 slots][128 wg][64 row][8 col]  (4 x 128 KiB rotating, sentinel-tagged)
#define WP_ELEMS    (256*48*64*8)
#define BIAS_OFF    ((size_t)WP_ELEMS * 2)
#define HBUF_OFF    (BIAS_OFF + 4096 * 4)
#define SLOT_HALVES 65536
#define SLOT_BYTES  131072

__device__ __forceinline__ float sigmoidf_(float v) {
    return 1.0f / (1.0f + __expf(-v));
}
__device__ __forceinline__ float tanhf_(float v) {
    return 1.0f - 2.0f / (1.0f + __expf(2.0f * v));
}

// System-scope (L1/L2-bypass, MALL-coherent) 16B load / store.
__device__ __forceinline__ f16x8 uload16(const void* p) {
    f16x8 r;
    asm volatile("global_load_dwordx4 %0, %1, off sc0 sc1"
                 : "=v"(r) : "v"(p) : "memory");
    return r;
}
__device__ __forceinline__ void ustore16(void* p, f32x4 v) {
    asm volatile("global_store_dwordx4 %0, %1, off sc0 sc1"
                 :: "v"(p), "v"(v) : "memory");
}

// Counted vmcnt wait (in-order retirement: upper bound, drain-safe) + sched fence
#define WAITV(N) do { asm volatile("s_waitcnt vmcnt(" #N ")" ::: "memory"); \
                      __builtin_amdgcn_sched_barrier(0); } while (0)

// sentinel = 0xFFFFFFFF per dword (fp16 -NaN pair; |h|<1 so never valid)
__device__ __forceinline__ bool stale8(f16x8 v) {
    u32x4 u = __builtin_bit_cast(u32x4, v);
    return (u[0] == 0xFFFFFFFFu) | (u[1] == 0xFFFFFFFFu) |
           (u[2] == 0xFFFFFFFFu) | (u[3] == 0xFFFFFFFFu);
}

// Packed col Np = wg*32 + gate*8 + c  <->  orig col n = gate*1024 + wg*8 + c.
// Wp8[(tile*48 + kb)*64 + lane] = Wfull[kb*32 + (lane>>4)*8 + j][orig(tile*16 + (lane&15))]
__global__ void pack_w_kernel(const float* __restrict__ Wi, const float* __restrict__ Wh,
                              _Float16* __restrict__ Wp)
{
    int d = blockIdx.x * blockDim.x + threadIdx.x;   // 0 .. 786431
    int tn   = d / 3072;
    int r    = d % 3072;
    int kb   = r / 64;
    int lane = r % 64;
    int kg = lane >> 4, lm = lane & 15;
    int Np = tn * 16 + lm;
    int g    = Np >> 5;
    int lc   = Np & 31;
    int gate = lc >> 3, c = lc & 7;
    int n  = gate * Hdim + g * 8 + c;
    int k0 = kb * 32 + kg * 8;
    f16x8 v;
#pragma unroll
    for (int j = 0; j < 8; ++j) {
        int k = k0 + j;
        float w = (k < Fdim) ? Wi[(long)k * 4096 + n] : Wh[(long)(k - Fdim) * 4096 + n];
        v[j] = (_Float16)w;
    }
    ((f16x8*)Wp)[d] = v;
}

__global__ void pack_misc_kernel(const float* __restrict__ bh, const float* __restrict__ h0,
                                 float* __restrict__ bias_p, _Float16* __restrict__ hbuf)
{
    int t = blockIdx.x * blockDim.x + threadIdx.x;   // 0 .. 65535
    if (t < 4096) {
        int g = t >> 5, lc = t & 31;
        int gate = lc >> 3, c = lc & 7;
        bias_p[t] = bh[gate * Hdim + g * 8 + c];
    }
    {   // slot 0 = h(0), compact layout [wg][row][col]
        int wgp = t >> 9;
        int b   = (t >> 3) & 63;
        int c   = t & 7;
        hbuf[t] = (_Float16)h0[b * Hdim + wgp * 8 + c];
    }
    {   // slots 1..3 = sentinel (re-armed every launch; graph-replay safe)
        unsigned int* up = (unsigned int*)(hbuf + SLOT_HALVES);
        up[t] = 0xFFFFFFFFu;                          // slots 1,2 (65536 u32)
        if (t < 32768) up[65536 + t] = 0xFFFFFFFFu;   // slot 3
    }
}

__global__ __launch_bounds__(NTHR, 1)
void lstm_kernel(const float* __restrict__ x, const float* __restrict__ c0,
                 const f16x8* __restrict__ Wp8, const float* __restrict__ bias_p,
                 _Float16* __restrict__ hbuf, float* __restrict__ out)
{
    __shared__ f16x8 wlds[2 * NKB * 64];              // 96 KiB weight slice
    __shared__ float zlds[Bdim][33];                  // wave-private 16-row slices

    const int wg   = (blockIdx.x & 7) * 16 + (blockIdx.x >> 3);  // XCD-grouped
    const int tid  = threadIdx.x;
    const int wave = tid >> 6;
    const int lane = tid & 63;
    const int kg = lane >> 4;
    const int lm = lane & 15;

    // ---- stage the WG's weight slice into LDS once ----
    {
        const f16x8* src = Wp8 + (size_t)wg * 2 * NKB * 64;
        for (int e = tid; e < 2 * NKB * 64; e += NTHR) wlds[e] = src[e];
    }

    const float bias0 = bias_p[wg * 32 + lm];
    const float bias1 = bias_p[wg * 32 + 16 + lm];

    // gate ownership: lane owns row grow = 16w + (l>>2), cols gjl, gjl+1
    const int grow = wave * 16 + (lane >> 2);
    const int gjl  = (lane & 3) * 2;
    float cc0 = c0[grow * Hdim + wg * 8 + gjl];
    float cc1 = c0[grow * Hdim + wg * 8 + gjl + 1];

    const int arow = wave * 16 + lm;                  // MFMA A-operand row (batch)
    const float* __restrict__ xrow = x + (size_t)arow * Tdim * Fdim + kg * 8;

    // reader base: packet (kb*4+kg) at + kb*4096; per-lane offset kg*1024 + arow*16
    char* __restrict__ hb  = (char*)hbuf;
    const char* __restrict__ hrd = hb + (size_t)kg * 1024 + (size_t)arow * 16;
    // writer/cleaner packet offset (lanes with (lane&3)==0 own one row-packet)
    const size_t mypkt = (size_t)wg * 1024 + (size_t)grow * 16;

    __syncthreads();                                  // wlds ready; no loop barriers after

    for (int t = 0; t < Tdim; ++t) {
        const int slot  = t & 3;
        const int wslot = (t + 1) & 3;
        const int cslot = (t + 2) & 3;

        // ---- pre-clear slot t+2 to sentinel (acked before this step's publish) ----
        if (!(lane & 3)) {
            u32x4 sv = {0xFFFFFFFFu, 0xFFFFFFFFu, 0xFFFFFFFFu, 0xFFFFFFFFu};
            ustore16(hb + (size_t)cslot * SLOT_BYTES + mypkt,
                     __builtin_bit_cast(f32x4, sv));
        }

        f32x4 acc0a = {bias0, bias0, bias0, bias0};
        f32x4 acc1a = {bias1, bias1, bias1, bias1};
        f32x4 acc0b = {0.f, 0.f, 0.f, 0.f};
        f32x4 acc1b = {0.f, 0.f, 0.f, 0.f};

        // ---- x part of K: load + cvt + MFMA (overlaps peers' h(t) publish) ----
        {
            const float* xt = xrow + (size_t)t * Fdim;
#pragma unroll 8
            for (int kb = 0; kb < NXKB; ++kb) {
                const f32x4* ap = (const f32x4*)(xt + kb * 32);
                f32x4 lo = ap[0];
                f32x4 hi = ap[1];
                f16x8 a;
#pragma unroll
                for (int j = 0; j < 4; ++j) { a[j] = (_Float16)lo[j]; a[4 + j] = (_Float16)hi[j]; }
                f16x8 bf0 = wlds[kb * 64 + lane];
                f16x8 bf1 = wlds[NKB * 64 + kb * 64 + lane];
                if (kb & 1) { acc0b = MFMA(a, bf0, acc0b); acc1b = MFMA(a, bf1, acc1b); }
                else        { acc0a = MFMA(a, bf0, acc0a); acc1a = MFMA(a, bf1, acc1a); }
            }
        }

        // ---- h part of K: counted-vmcnt pipeline; poll == data load (sentinel check) ----
        {
            const char* hq = hrd + (size_t)slot * SLOT_BYTES;
            f16x8 hA[8], hB[8];

#define HLOAD(BASE, H)                                                  \
            _Pragma("unroll")                                           \
            for (int k = 0; k < 8; ++k)                                 \
                H[k] = uload16(hq + (size_t)((BASE) + k) * 4096);

#define HCHECK(BASE, H)                                                 \
            {                                                           \
                bool st[8]; bool any = false;                           \
                _Pragma("unroll")                                       \
                for (int k = 0; k < 8; ++k) { st[k] = stale8(H[k]); any |= st[k]; } \
                while (__any(any)) {                                    \
                    __builtin_amdgcn_s_sleep(1);                        \
                    _Pragma("unroll")                                   \
                    for (int k = 0; k < 8; ++k)                         \
                        if (st[k]) H[k] = uload16(hq + (size_t)((BASE) + k) * 4096); \
                    asm volatile("s_waitcnt vmcnt(0)" ::: "memory");    \
                    __builtin_amdgcn_sched_barrier(0);                  \
                    any = false;                                        \
                    _Pragma("unroll")                                   \
                    for (int k = 0; k < 8; ++k) { st[k] = stale8(H[k]); any |= st[k]; } \
                }                                                       \
            }

#define HGROUP(BASE, H)                                                 \
            _Pragma("unroll")                                           \
            for (int k = 0; k < 8; ++k) {                               \
                int kb = (BASE) + k;                                    \
                f16x8 bf0 = wlds[(NXKB + kb) * 64 + lane];              \
                f16x8 bf1 = wlds[NKB * 64 + (NXKB + kb) * 64 + lane];   \
                if (kb & 1) { acc0b = MFMA(H[k], bf0, acc0b); acc1b = MFMA(H[k], bf1, acc1b); } \
                else        { acc0a = MFMA(H[k], bf0, acc0a); acc1a = MFMA(H[k], bf1, acc1a); } \
            }

            HLOAD(0,  hA);                            // 8 outstanding (+ stale junk)
            HLOAD(8,  hB);                            // 16
            WAITV(8);                                 // g0 retired (junk drained)
            HCHECK(0,  hA);
            HGROUP(0,  hA);
            HLOAD(16, hA);                            // reuse freed regs
            WAITV(8);                                 // g1 retired
            HCHECK(8,  hB);
            HGROUP(8,  hB);
            HLOAD(24, hB);
            WAITV(8);                                 // g2 retired
            HCHECK(16, hA);
            HGROUP(16, hA);
            WAITV(0);                                 // g3 retired
            HCHECK(24, hB);
            HGROUP(24, hB);
#undef HLOAD
#undef HCHECK
#undef HGROUP
        }
        f32x4 z0 = acc0a + acc0b;
        f32x4 z1 = acc1a + acc1b;

        // D layout: row = (lane>>4)*4 + r, col = lane&15  (wave-private rows)
        {
            int rbase = wave * 16 + kg * 4;
#pragma unroll
            for (int r = 0; r < 4; ++r) {
                zlds[rbase + r][lm]      = z0[r];
                zlds[rbase + r][16 + lm] = z1[r];
            }
        }
        asm volatile("s_waitcnt lgkmcnt(0)" ::: "memory");
        __builtin_amdgcn_sched_barrier(0);

        // ---- gates: 2 cols per lane (i=c, f=8+c, g=16+c, o=24+c) ----
        float hv0, hv1;
        {
            float i0 = sigmoidf_(zlds[grow][gjl]);
            float f0 = sigmoidf_(zlds[grow][8 + gjl]);
            float g0 = tanhf_(zlds[grow][16 + gjl]);
            float o0 = sigmoidf_(zlds[grow][24 + gjl]);
            cc0 = f0 * cc0 + i0 * g0;
            hv0 = o0 * tanhf_(cc0);

            float i1 = sigmoidf_(zlds[grow][gjl + 1]);
            float f1 = sigmoidf_(zlds[grow][8 + gjl + 1]);
            float g1 = tanhf_(zlds[grow][16 + gjl + 1]);
            float o1 = sigmoidf_(zlds[grow][24 + gjl + 1]);
            cc1 = f1 * cc1 + i1 * g1;
            hv1 = o1 * tanhf_(cc1);
        }

        // ---- publish h(t+1): gather row's 4x4B -> one 16B store, fire-and-forget ----
        {
            union { _Float16 h[2]; unsigned int u; } pk;
            pk.h[0] = (_Float16)hv0; pk.h[1] = (_Float16)hv1;
            const int lb = lane & ~3;
            unsigned int q0 = __shfl(pk.u, lb);
            unsigned int q1 = __shfl(pk.u, lb + 1);
            unsigned int q2 = __shfl(pk.u, lb + 2);
            unsigned int q3 = __shfl(pk.u, lb + 3);
            if (!(lane & 3)) {
                u32x4 pkt = {q0, q1, q2, q3};
                ustore16(hb + (size_t)wslot * SLOT_BYTES + mypkt,
                         __builtin_bit_cast(f32x4, pkt));
            }
        }

        // ---- out store (plain cached; drained by next step's h-phase waits) ----
        {
            float2 ov; ov.x = hv0; ov.y = hv1;
            *(float2*)(out + ((size_t)grow * Tdim + t) * Hdim + wg * 8 + gjl) = ov;
        }
    }
}

extern "C" void kernel_launch(void* const* d_in, const int* in_sizes, int n_in,
                              void* d_out, int out_size, void* d_ws, size_t ws_size,
                              hipStream_t stream)
{
    const float* x  = (const float*)d_in[0];
    const float* c0 = (const float*)d_in[1];
    const float* h0 = (const float*)d_in[2];
    const float* Wi = (const float*)d_in[3];
    const float* Wh = (const float*)d_in[4];
    const float* bh = (const float*)d_in[5];
    float* out = (float*)d_out;

    char* ws = (char*)d_ws;
    _Float16* Wp     = (_Float16*)(ws);
    float*    bias_p = (float*)(ws + BIAS_OFF);
    _Float16* hbuf   = (_Float16*)(ws + HBUF_OFF);

    hipLaunchKernelGGL(pack_w_kernel,    dim3(3072), dim3(256), 0, stream, Wi, Wh, Wp);
    hipLaunchKernelGGL(pack_misc_kernel, dim3(256),  dim3(256), 0, stream, bh, h0, bias_p, hbuf);
    hipLaunchKernelGGL(lstm_kernel, dim3(NWG), dim3(NTHR), 0, stream,
                       x, c0, (const f16x8*)Wp, bias_p, hbuf, out);
}

// Round 10
// 3379.773 us; speedup vs baseline: 1.0947x; 1.0761x over previous
//
#include <hip/hip_runtime.h>

#define Bdim 64
#define Tdim 512
#define Fdim 512
#define Hdim 1024
#define NKB  48          // K-blocks of 32: 16 for x (K=512) + 32 for h (K=1024)
#define NXKB 16
#define NHKB 32
#define NWG  128
#define NTHR 256

typedef __attribute__((ext_vector_type(8))) _Float16     f16x8;
typedef __attribute__((ext_vector_type(4))) float        f32x4;
typedef __attribute__((ext_vector_type(4))) unsigned int u32x4;

#define MFMA(a, b, c) __builtin_amdgcn_mfma_f32_16x16x32_f16((a), (b), (c), 0, 0, 0)

// ---- workspace layout (bytes) ----
// Wp    : fp16 fragment-linear weights, 12.6 MB
// bias_p: fp32[4096]
// hbuf  : fp16[513 slots][128 wg][64 row][8 col] ring, 67.2 MB.
//         Each slot address is written exactly ONCE per launch (publish of
//         h(t) into slot t) and read only after the flag gate -> an L2 copy
//         can only ever have been fetched post-publish (fresh). This makes
//         plain-L2-cached reads safe with zero invalidates.
// flags : uint[NWG] padded to one 128B line each
#define WP_ELEMS    (256*48*64*8)
#define BIAS_OFF    ((size_t)WP_ELEMS * 2)
#define HBUF_OFF    (BIAS_OFF + 4096 * 4)
#define SLOT_BYTES  131072
#define NRING       513
#define FLAG_OFF    (HBUF_OFF + (size_t)NRING * SLOT_BYTES)
#define FLAG_STRIDE 32                               // uints (128 B) per flag

__device__ __forceinline__ float sigmoidf_(float v) {
    return 1.0f / (1.0f + __expf(-v));
}
__device__ __forceinline__ float tanhf_(float v) {
    return 1.0f - 2.0f / (1.0f + __expf(2.0f * v));
}

// L1-bypass, L2-CACHED 16B load: first reader per XCD fetches the line from
// MALL into the XCD L2; the other ~15 WGs on that XCD hit L2.
__device__ __forceinline__ f16x8 uload16_l2(const void* p) {
    f16x8 r;
    asm volatile("global_load_dwordx4 %0, %1, off sc0"
                 : "=v"(r) : "v"(p) : "memory");
    return r;
}
// Write-through to MALL (cross-XCD visible) 16B store.
__device__ __forceinline__ void ustore16(void* p, f32x4 v) {
    asm volatile("global_store_dwordx4 %0, %1, off sc0 sc1"
                 :: "v"(p), "v"(v) : "memory");
}

// Counted vmcnt wait (in-order retirement) + scheduling fence (rule #18)
#define WAITV(N) do { asm volatile("s_waitcnt vmcnt(" #N ")" ::: "memory"); \
                      __builtin_amdgcn_sched_barrier(0); } while (0)

// Packed col Np = wg*32 + gate*8 + c  <->  orig col n = gate*1024 + wg*8 + c.
// Wp8[(tile*48 + kb)*64 + lane] = Wfull[kb*32 + (lane>>4)*8 + j][orig(tile*16 + (lane&15))]
__global__ void pack_w_kernel(const float* __restrict__ Wi, const float* __restrict__ Wh,
                              _Float16* __restrict__ Wp)
{
    int d = blockIdx.x * blockDim.x + threadIdx.x;   // 0 .. 786431
    int tn   = d / 3072;
    int r    = d % 3072;
    int kb   = r / 64;
    int lane = r % 64;
    int kg = lane >> 4, lm = lane & 15;
    int Np = tn * 16 + lm;
    int g    = Np >> 5;
    int lc   = Np & 31;
    int gate = lc >> 3, c = lc & 7;
    int n  = gate * Hdim + g * 8 + c;
    int k0 = kb * 32 + kg * 8;
    f16x8 v;
#pragma unroll
    for (int j = 0; j < 8; ++j) {
        int k = k0 + j;
        float w = (k < Fdim) ? Wi[(long)k * 4096 + n] : Wh[(long)(k - Fdim) * 4096 + n];
        v[j] = (_Float16)w;
    }
    ((f16x8*)Wp)[d] = v;
}

__global__ void pack_misc_kernel(const float* __restrict__ bh, const float* __restrict__ h0,
                                 float* __restrict__ bias_p, _Float16* __restrict__ hbuf,
                                 unsigned int* __restrict__ flags)
{
    int t = blockIdx.x * blockDim.x + threadIdx.x;   // 0 .. 65535
    if (t < NWG) flags[t * FLAG_STRIDE] = 0u;        // re-armed every launch
    if (t < 4096) {
        int g = t >> 5, lc = t & 31;
        int gate = lc >> 3, c = lc & 7;
        bias_p[t] = bh[gate * Hdim + g * 8 + c];
    }
    {   // ring slot 0 = h(0), compact layout [wg][row][col]
        int wgp = t >> 9;
        int b   = (t >> 3) & 63;
        int c   = t & 7;
        hbuf[t] = (_Float16)h0[b * Hdim + wgp * 8 + c];
    }
}

__global__ __launch_bounds__(NTHR, 1)
void lstm_kernel(const float* __restrict__ x, const float* __restrict__ c0,
                 const f16x8* __restrict__ Wp8, const float* __restrict__ bias_p,
                 _Float16* __restrict__ hbuf, unsigned int* __restrict__ flags,
                 float* __restrict__ out)
{
    __shared__ f16x8 wlds[2 * NKB * 64];              // 96 KiB weight slice
    __shared__ float zlds[Bdim][33];                  // wave-private 16-row slices

    const int wg   = (blockIdx.x & 7) * 16 + (blockIdx.x >> 3);  // XCD-grouped
    const int tid  = threadIdx.x;
    const int wave = tid >> 6;
    const int lane = tid & 63;
    const int kg = lane >> 4;
    const int lm = lane & 15;

    // ---- stage the WG's weight slice into LDS once ----
    {
        const f16x8* src = Wp8 + (size_t)wg * 2 * NKB * 64;
        for (int e = tid; e < 2 * NKB * 64; e += NTHR) wlds[e] = src[e];
    }

    const float bias0 = bias_p[wg * 32 + lm];
    const float bias1 = bias_p[wg * 32 + 16 + lm];

    // gate ownership: lane owns row grow = 16w + (l>>2), cols gjl, gjl+1
    const int grow = wave * 16 + (lane >> 2);
    const int gjl  = (lane & 3) * 2;
    float cc0 = c0[grow * Hdim + wg * 8 + gjl];
    float cc1 = c0[grow * Hdim + wg * 8 + gjl + 1];

    const int arow = wave * 16 + lm;                  // MFMA A-operand row (batch)
    const float* __restrict__ xrow = x + (size_t)arow * Tdim * Fdim + kg * 8;

    // reader per-lane base inside a slot; packet kb at +kb*4096
    char* __restrict__ hb  = (char*)hbuf;
    const char* __restrict__ hrd = hb + (size_t)kg * 1024 + (size_t)arow * 16;
    // writer packet offset (lanes with (lane&3)==0 own one row-packet)
    const size_t mypkt = (size_t)wg * 1024 + (size_t)grow * 16;

    __syncthreads();                                  // wlds ready

    for (int t = 0; t < Tdim; ++t) {
        const unsigned int gen = (unsigned int)t;

        f32x4 acc0a = {bias0, bias0, bias0, bias0};
        f32x4 acc1a = {bias1, bias1, bias1, bias1};
        f32x4 acc0b = {0.f, 0.f, 0.f, 0.f};
        f32x4 acc1b = {0.f, 0.f, 0.f, 0.f};

        // ---- x part of K: load + cvt + MFMA (overlaps peers' h(t) publish) ----
        {
            const float* xt = xrow + (size_t)t * Fdim;
#pragma unroll 8
            for (int kb = 0; kb < NXKB; ++kb) {
                const f32x4* ap = (const f32x4*)(xt + kb * 32);
                f32x4 lo = ap[0];
                f32x4 hi = ap[1];
                f16x8 a;
#pragma unroll
                for (int j = 0; j < 4; ++j) { a[j] = (_Float16)lo[j]; a[4 + j] = (_Float16)hi[j]; }
                f16x8 bf0 = wlds[kb * 64 + lane];
                f16x8 bf1 = wlds[NKB * 64 + kb * 64 + lane];
                if (kb & 1) { acc0b = MFMA(a, bf0, acc0b); acc1b = MFMA(a, bf1, acc1b); }
                else        { acc0a = MFMA(a, bf0, acc0a); acc1a = MFMA(a, bf1, acc1a); }
            }
        }

        // ---- wave 0 polls flags (target 4*gen: per-wave increments); others wait at (A) ----
        if (t && wave == 0) {
            const unsigned int target = 4u * gen;
            while (true) {
                unsigned int f0 = __hip_atomic_load(flags + (size_t)lane * FLAG_STRIDE,
                                                    __ATOMIC_RELAXED, __HIP_MEMORY_SCOPE_AGENT);
                unsigned int f1 = __hip_atomic_load(flags + (size_t)(64 + lane) * FLAG_STRIDE,
                                                    __ATOMIC_RELAXED, __HIP_MEMORY_SCOPE_AGENT);
                if (__all(f0 >= target && f1 >= target)) break;
                __builtin_amdgcn_s_sleep(1);
            }
        }
        __syncthreads();                              // (A) h(t) globally published

        // ---- h part of K: counted-vmcnt pipeline; L2-cached reads (16x shared/XCD) ----
        {
            const char* hq = hrd + (size_t)t * SLOT_BYTES;
            f16x8 hA[8], hB[8];

#define HLOAD(BASE, H)                                                  \
            _Pragma("unroll")                                           \
            for (int k = 0; k < 8; ++k)                                 \
                H[k] = uload16_l2(hq + (size_t)((BASE) + k) * 4096);

#define HGROUP(BASE, H)                                                 \
            _Pragma("unroll")                                           \
            for (int k = 0; k < 8; ++k) {                               \
                int kb = (BASE) + k;                                    \
                f16x8 bf0 = wlds[(NXKB + kb) * 64 + lane];              \
                f16x8 bf1 = wlds[NKB * 64 + (NXKB + kb) * 64 + lane];   \
                if (kb & 1) { acc0b = MFMA(H[k], bf0, acc0b); acc1b = MFMA(H[k], bf1, acc1b); } \
                else        { acc0a = MFMA(H[k], bf0, acc0a); acc1a = MFMA(H[k], bf1, acc1a); } \
            }

            HLOAD(0,  hA);                            // 8 outstanding
            HLOAD(8,  hB);                            // 16
            WAITV(8);                                 // g0 retired
            HGROUP(0,  hA);
            HLOAD(16, hA);                            // reuse freed regs
            WAITV(8);                                 // g1 retired
            HGROUP(8,  hB);
            HLOAD(24, hB);
            WAITV(8);                                 // g2 retired
            HGROUP(16, hA);
            WAITV(0);                                 // g3 retired
            HGROUP(24, hB);
#undef HLOAD
#undef HGROUP
        }
        f32x4 z0 = acc0a + acc0b;
        f32x4 z1 = acc1a + acc1b;

        // D layout: row = (lane>>4)*4 + r, col = lane&15  (wave-private rows)
        {
            int rbase = wave * 16 + kg * 4;
#pragma unroll
            for (int r = 0; r < 4; ++r) {
                zlds[rbase + r][lm]      = z0[r];
                zlds[rbase + r][16 + lm] = z1[r];
            }
        }
        asm volatile("s_waitcnt lgkmcnt(0)" ::: "memory");
        __builtin_amdgcn_sched_barrier(0);

        // ---- gates: 2 cols per lane (i=c, f=8+c, g=16+c, o=24+c) ----
        float hv0, hv1;
        {
            float i0 = sigmoidf_(zlds[grow][gjl]);
            float f0 = sigmoidf_(zlds[grow][8 + gjl]);
            float g0 = tanhf_(zlds[grow][16 + gjl]);
            float o0 = sigmoidf_(zlds[grow][24 + gjl]);
            cc0 = f0 * cc0 + i0 * g0;
            hv0 = o0 * tanhf_(cc0);

            float i1 = sigmoidf_(zlds[grow][gjl + 1]);
            float f1 = sigmoidf_(zlds[grow][8 + gjl + 1]);
            float g1 = tanhf_(zlds[grow][16 + gjl + 1]);
            float o1 = sigmoidf_(zlds[grow][24 + gjl + 1]);
            cc1 = f1 * cc1 + i1 * g1;
            hv1 = o1 * tanhf_(cc1);
        }

        // ---- publish h(t+1) into ring slot t+1: 4-lane gather -> one 16B store ----
        {
            union { _Float16 h[2]; unsigned int u; } pk;
            pk.h[0] = (_Float16)hv0; pk.h[1] = (_Float16)hv1;
            const int lb = lane & ~3;
            unsigned int q0 = __shfl(pk.u, lb);
            unsigned int q1 = __shfl(pk.u, lb + 1);
            unsigned int q2 = __shfl(pk.u, lb + 2);
            unsigned int q3 = __shfl(pk.u, lb + 3);
            if (!(lane & 3)) {
                u32x4 pkt = {q0, q1, q2, q3};
                ustore16(hb + (size_t)(t + 1) * SLOT_BYTES + mypkt,
                         __builtin_bit_cast(f32x4, pkt));
            }
        }
        // per-wave drain + per-wave flag increment (no intra-WG barrier needed)
        asm volatile("s_waitcnt vmcnt(0)" ::: "memory");
        if (lane == 0)
            __hip_atomic_fetch_add(flags + (size_t)wg * FLAG_STRIDE, 1u,
                                   __ATOMIC_RELAXED, __HIP_MEMORY_SCOPE_AGENT);

        // ---- out store (plain cached, off critical path) ----
        {
            float2 ov; ov.x = hv0; ov.y = hv1;
            *(float2*)(out + ((size_t)grow * Tdim + t) * Hdim + wg * 8 + gjl) = ov;
        }
    }
}

extern "C" void kernel_launch(void* const* d_in, const int* in_sizes, int n_in,
                              void* d_out, int out_size, void* d_ws, size_t ws_size,
                              hipStream_t stream)
{
    const float* x  = (const float*)d_in[0];
    const float* c0 = (const float*)d_in[1];
    const float* h0 = (const float*)d_in[2];
    const float* Wi = (const float*)d_in[3];
    const float* Wh = (const float*)d_in[4];
    const float* bh = (const float*)d_in[5];
    float* out = (float*)d_out;

    char* ws = (char*)d_ws;
    _Float16*     Wp     = (_Float16*)(ws);
    float*        bias_p = (float*)(ws + BIAS_OFF);
    _Float16*     hbuf   = (_Float16*)(ws + HBUF_OFF);
    unsigned int* flags  = (unsigned int*)(ws + FLAG_OFF);

    hipLaunchKernelGGL(pack_w_kernel,    dim3(3072), dim3(256), 0, stream, Wi, Wh, Wp);
    hipLaunchKernelGGL(pack_misc_kernel, dim3(256),  dim3(256), 0, stream, bh, h0, bias_p, hbuf, flags);
    hipLaunchKernelGGL(lstm_kernel, dim3(NWG), dim3(NTHR), 0, stream,
                       x, c0, (const f16x8*)Wp, bias_p, hbuf, flags, out);
}